// Round 1
// baseline (124.790 us; speedup 1.0000x reference)
//
#include <hip/hip_runtime.h>

// AutoCorrelation attention, FFT-based.
// B=16, L=4096, D=64, k=24 (= floor(3*ln(4096))).
//
// Pipeline:
//   1. transpose Q,K,V [B,L,D] -> [B,D,L]  (coalesced tile transpose)
//   2. per (b,d) row: z=q+ik, DIF FFT (natural->bitrev), pointwise
//      P = Qf*conj(Kf) computed in bitrev domain, DIT inverse FFT
//      (bitrev->natural), top-24 + softmax, shifted-gather of V row.
//      Writes At [B,D,L] (aliases Qt slab; safe: row read fully first).
//   3. transpose At -> A [B,L,D].

#define FFT_N   4096
#define LOG2N   12
#define TOPK    24
#define PI2     6.28318530717958647692f

__global__ __launch_bounds__(256) void transpose64(const float* __restrict__ in,
                                                   float* __restrict__ out,
                                                   int R, int C) {
  // [R x C] -> [C x R] per batch (blockIdx.y), 64x64 tiles.
  __shared__ float tile[64][65];
  int tiles_c = C >> 6;
  int tr = blockIdx.x / tiles_c;
  int tc = blockIdx.x - tr * tiles_c;
  const float* inb = in + (size_t)blockIdx.y * R * C;
  float* outb = out + (size_t)blockIdx.y * R * C;
  int tx = threadIdx.x & 63;
  int ty = threadIdx.x >> 6;        // 0..3
  int r0 = tr << 6, c0 = tc << 6;
#pragma unroll
  for (int i = 0; i < 16; ++i) {
    int r = (i << 2) + ty;
    tile[r][tx] = inb[(size_t)(r0 + r) * C + (c0 + tx)];
  }
  __syncthreads();
#pragma unroll
  for (int i = 0; i < 16; ++i) {
    int r = (i << 2) + ty;
    outb[(size_t)(c0 + r) * R + (r0 + tx)] = tile[tx][r];
  }
}

__global__ __launch_bounds__(256) void corr_kernel(const float* __restrict__ Qt,
                                                   const float* __restrict__ Kt,
                                                   const float* __restrict__ Vt,
                                                   float* __restrict__ At) {
  __shared__ float re[FFT_N];
  __shared__ float im[FFT_N];
  __shared__ float sval[256];
  __shared__ int   sidx[256];
  __shared__ float swk[TOPK];
  __shared__ int   sik[TOPK];

  const int tid = threadIdx.x;
  const size_t row = (size_t)blockIdx.x * FFT_N;   // blockIdx.x = b*64 + d

  // ---- load z = q + i*k ----
  for (int j = tid; j < FFT_N; j += 256) {
    re[j] = Qt[row + j];
    im[j] = Kt[row + j];
  }
  __syncthreads();

  // ---- forward DIF FFT (e^{-2pi i}), natural input -> bit-reversed output ----
  for (int s = 0; s < LOG2N; ++s) {
    int sh = (LOG2N - 1) - s;       // log2(half)
    int half = 1 << sh;
    float base = -PI2 / (float)(half << 1);
    for (int j = tid; j < (FFT_N >> 1); j += 256) {
      int p = j & (half - 1);
      int i0 = ((j >> sh) << (sh + 1)) + p;
      int i1 = i0 + half;
      float ar = re[i0], ai = im[i0];
      float br = re[i1], bi = im[i1];
      re[i0] = ar + br; im[i0] = ai + bi;
      float sr = ar - br, si = ai - bi;
      float cs, sn;
      __sincosf(base * (float)p, &sn, &cs);
      re[i1] = sr * cs - si * sn;
      im[i1] = sr * sn + si * cs;
    }
    __syncthreads();
  }

  // ---- pointwise: P[f] = Qf*conj(Kf) = i/4 (a + conj(b))(conj(a) - b),
  //      a=Z[f], b=Z[(N-f)%N]; done in bit-reversed layout. Fold in 1/(4N). ----
  {
    const float scale = 0.25f / (float)FFT_N;
    float pr[16], pq[16];
#pragma unroll
    for (int j = 0; j < 16; ++j) {
      int p = tid + (j << 8);
      int f = __brev((unsigned)p) >> (32 - LOG2N);
      int f2 = (FFT_N - f) & (FFT_N - 1);
      int pp = __brev((unsigned)f2) >> (32 - LOG2N);
      float ar = re[p], ai = im[p];
      float br = re[pp], bi = im[pp];
      float ur = ar + br, ui = ai - bi;     // a + conj(b)
      float vr = ar - br, vi = -ai - bi;    // conj(a) - b
      float xr = ur * vr - ui * vi;
      float xi = ur * vi + ui * vr;
      pr[j] = -xi * scale;                  // i*(x) -> (-xi, xr)
      pq[j] = xr * scale;
    }
    __syncthreads();
#pragma unroll
    for (int j = 0; j < 16; ++j) {
      int p = tid + (j << 8);
      re[p] = pr[j];
      im[p] = pq[j];
    }
    __syncthreads();
  }

  // ---- inverse DIT FFT (e^{+2pi i}), bit-reversed input -> natural output ----
  for (int s = 0; s < LOG2N; ++s) {
    int half = 1 << s;
    float base = PI2 / (float)(half << 1);
    for (int j = tid; j < (FFT_N >> 1); j += 256) {
      int p = j & (half - 1);
      int i0 = ((j >> s) << (s + 1)) + p;
      int i1 = i0 + half;
      float cs, sn;
      __sincosf(base * (float)p, &sn, &cs);
      float b0r = re[i1], b0i = im[i1];
      float br = b0r * cs - b0i * sn;
      float bi = b0r * sn + b0i * cs;
      float ar = re[i0], ai = im[i0];
      re[i0] = ar + br; im[i0] = ai + bi;
      re[i1] = ar - br; im[i1] = ai - bi;
    }
    __syncthreads();
  }
  // re[tau] now holds Rxx[tau] (1/N and 1/4 already folded in).

  // ---- iterative top-24 (argmax 24 times) ----
  for (int t = 0; t < TOPK; ++t) {
    float bv = -1e30f;
    int bi = 0;
#pragma unroll
    for (int j = 0; j < 16; ++j) {
      int p = tid + (j << 8);
      float v = re[p];
      if (v > bv) { bv = v; bi = p; }
    }
    sval[tid] = bv; sidx[tid] = bi;
    __syncthreads();
    for (int sft = 128; sft > 0; sft >>= 1) {
      if (tid < sft) {
        float v2 = sval[tid + sft];
        int i2 = sidx[tid + sft];
        if (v2 > sval[tid] || (v2 == sval[tid] && i2 < sidx[tid])) {
          sval[tid] = v2; sidx[tid] = i2;
        }
      }
      __syncthreads();
    }
    if (tid == 0) {
      swk[t] = sval[0];
      sik[t] = sidx[0];
      re[sidx[0]] = -1e30f;   // exclude from next rounds
    }
    __syncthreads();
  }

  // ---- softmax over the 24 raw correlation values ----
  if (tid == 0) {
    float m0 = swk[0];        // descending order -> swk[0] is max
    float ssum = 0.f;
    float e[TOPK];
#pragma unroll
    for (int t = 0; t < TOPK; ++t) { e[t] = __expf(swk[t] - m0); ssum += e[t]; }
    float inv = 1.0f / ssum;
#pragma unroll
    for (int t = 0; t < TOPK; ++t) swk[t] = e[t] * inv;
  }
  __syncthreads();

  // ---- shifted gather of V row: A[l] = sum_k w_k * V[(l + i_k) % N] ----
  for (int j = tid; j < FFT_N; j += 256) im[j] = Vt[row + j];
  __syncthreads();
  for (int j = tid; j < FFT_N; j += 256) {
    float acc = 0.f;
#pragma unroll
    for (int t = 0; t < TOPK; ++t)
      acc += swk[t] * im[(j + sik[t]) & (FFT_N - 1)];
    At[row + j] = acc;
  }
}

extern "C" void kernel_launch(void* const* d_in, const int* in_sizes, int n_in,
                              void* d_out, int out_size, void* d_ws, size_t ws_size,
                              hipStream_t stream) {
  const float* Q = (const float*)d_in[0];
  const float* K = (const float*)d_in[1];
  const float* V = (const float*)d_in[2];
  float* out = (float*)d_out;
  float* ws = (float*)d_ws;

  const int B = 16, L = 4096, D = 64;
  const size_t SLAB = (size_t)B * L * D;   // 4,194,304 floats
  float* Qt = ws;
  float* Kt = ws + SLAB;
  float* Vt = ws + 2 * SLAB;
  float* At = Qt;                          // alias: safe (row read before write)

  dim3 blk(256);
  // [B,L,D] -> [B,D,L]: R=L=4096, C=D=64 -> 64 tiles x B batches
  transpose64<<<dim3(64, B), blk, 0, stream>>>(Q, Qt, L, D);
  transpose64<<<dim3(64, B), blk, 0, stream>>>(K, Kt, L, D);
  transpose64<<<dim3(64, B), blk, 0, stream>>>(V, Vt, L, D);

  corr_kernel<<<dim3(B * D), blk, 0, stream>>>(Qt, Kt, Vt, At);

  // [B,D,L] -> [B,L,D]: R=D=64, C=L=4096
  transpose64<<<dim3(64, B), blk, 0, stream>>>(At, out, D, L);
}

// Round 2
// 104.452 us; speedup vs baseline: 1.1947x; 1.1947x over previous
//
#include <hip/hip_runtime.h>

// AutoCorrelation attention, radix-4 FFT version.
// B=16, L=4096, D=64, k=24.

#define FFT_N 4096
#define LOG2N 12
#define TOPK  24
#define PI2   6.28318530717958647692f

__device__ __forceinline__ int SW(int i) { return i ^ ((i >> 5) & 31); }

// base-4 digit reversal of a 12-bit index
__device__ __forceinline__ int drev4(int x) {
  unsigned r = __brev((unsigned)x) >> 20;          // bit-reverse 12 bits
  return (int)(((r & 0x555u) << 1) | ((r >> 1) & 0x555u));  // swap bit pairs
}

__global__ __launch_bounds__(256) void transpose64(const float* __restrict__ in,
                                                   float* __restrict__ out,
                                                   int R, int C) {
  __shared__ float tile[64][65];
  int tiles_c = C >> 6;
  int tr = blockIdx.x / tiles_c;
  int tc = blockIdx.x - tr * tiles_c;
  const float* inb = in + (size_t)blockIdx.y * R * C;
  float* outb = out + (size_t)blockIdx.y * R * C;
  int tx = threadIdx.x & 63;
  int ty = threadIdx.x >> 6;
  int r0 = tr << 6, c0 = tc << 6;
#pragma unroll
  for (int i = 0; i < 16; ++i) {
    int r = (i << 2) + ty;
    tile[r][tx] = inb[(size_t)(r0 + r) * C + (c0 + tx)];
  }
  __syncthreads();
#pragma unroll
  for (int i = 0; i < 16; ++i) {
    int r = (i << 2) + ty;
    outb[(size_t)(c0 + r) * R + (r0 + tx)] = tile[tx][r];
  }
}

__global__ __launch_bounds__(256, 4) void corr_kernel(const float* __restrict__ Qt,
                                                      const float* __restrict__ Kt,
                                                      const float* __restrict__ Vt,
                                                      float* __restrict__ At) {
  __shared__ float re[FFT_N];
  __shared__ float im[FFT_N];
  __shared__ float sv[2][4];
  __shared__ int   si[2][4];
  __shared__ float swk[TOPK];
  __shared__ int   sik[TOPK];
  __shared__ float sinv;

  const int tid = threadIdx.x;
  const size_t row = (size_t)blockIdx.x * FFT_N;

  // ---------- forward DIF stage 0 (L=4096, q=1024): global -> LDS ----------
  {
    const float cf = -PI2 / (float)FFT_N;
#pragma unroll
    for (int mm = 0; mm < 4; ++mm) {
      int j = tid + (mm << 8);
      float ar = Qt[row + j],        ai = Kt[row + j];
      float br = Qt[row + j + 1024], bi = Kt[row + j + 1024];
      float cr = Qt[row + j + 2048], ci = Kt[row + j + 2048];
      float dr = Qt[row + j + 3072], di = Kt[row + j + 3072];
      float t0r = ar + cr, t0i = ai + ci;
      float t1r = ar - cr, t1i = ai - ci;
      float t2r = br + dr, t2i = bi + di;
      float t3r = br - dr, t3i = bi - di;
      re[SW(j)] = t0r + t2r;  im[SW(j)] = t0i + t2i;
      float u1r = t1r + t3i, u1i = t1i - t3r;     // t1 - i*t3
      float u2r = t0r - t2r, u2i = t0i - t2i;
      float u3r = t1r - t3i, u3i = t1i + t3r;     // t1 + i*t3
      float ang = cf * (float)j;
      float s1, c1;  __sincosf(ang, &s1, &c1);
      float c2 = c1*c1 - s1*s1, s2 = 2.f*c1*s1;
      float c3 = c1*c2 - s1*s2, s3 = c1*s2 + s1*c2;
      re[SW(j + 1024)] = u1r*c1 - u1i*s1;  im[SW(j + 1024)] = u1r*s1 + u1i*c1;
      re[SW(j + 2048)] = u2r*c2 - u2i*s2;  im[SW(j + 2048)] = u2r*s2 + u2i*c2;
      re[SW(j + 3072)] = u3r*c3 - u3i*s3;  im[SW(j + 3072)] = u3r*s3 + u3i*c3;
    }
  }
  __syncthreads();

  // ---------- forward DIF stages (q = 256, 64, 16, 4, 1) ----------
  for (int lq = 8; lq >= 0; lq -= 2) {
    const int q = 1 << lq;
    const float cf = -PI2 / (float)(q << 2);
#pragma unroll
    for (int mm = 0; mm < 4; ++mm) {
      int j = tid + (mm << 8);
      int p = j & (q - 1);
      int base = ((j >> lq) << (lq + 2)) + p;
      int i0 = SW(base), i1 = SW(base + q), i2 = SW(base + 2*q), i3 = SW(base + 3*q);
      float ar = re[i0], ai = im[i0];
      float br = re[i1], bi = im[i1];
      float cr = re[i2], ci = im[i2];
      float dr = re[i3], di = im[i3];
      float t0r = ar + cr, t0i = ai + ci;
      float t1r = ar - cr, t1i = ai - ci;
      float t2r = br + dr, t2i = bi + di;
      float t3r = br - dr, t3i = bi - di;
      re[i0] = t0r + t2r;  im[i0] = t0i + t2i;
      float u1r = t1r + t3i, u1i = t1i - t3r;
      float u2r = t0r - t2r, u2i = t0i - t2i;
      float u3r = t1r - t3i, u3i = t1i + t3r;
      float ang = cf * (float)p;
      float s1, c1;  __sincosf(ang, &s1, &c1);
      float c2 = c1*c1 - s1*s1, s2 = 2.f*c1*s1;
      float c3 = c1*c2 - s1*s2, s3 = c1*s2 + s1*c2;
      re[i1] = u1r*c1 - u1i*s1;  im[i1] = u1r*s1 + u1i*c1;
      re[i2] = u2r*c2 - u2i*s2;  im[i2] = u2r*s2 + u2i*c2;
      re[i3] = u3r*c3 - u3i*s3;  im[i3] = u3r*s3 + u3i*c3;
    }
    __syncthreads();
  }

  // ---------- pointwise P = Qf*conj(Kf) (digit-reversed domain) ----------
  {
    const float scale = 0.25f / (float)FFT_N;
    float prr[16], pii[16];
#pragma unroll
    for (int mm = 0; mm < 16; ++mm) {
      int pos = tid + (mm << 8);
      int f  = drev4(pos);
      int f2 = (FFT_N - f) & (FFT_N - 1);
      int pp = drev4(f2);
      float ar = re[SW(pos)], ai = im[SW(pos)];
      float br = re[SW(pp)],  bi = im[SW(pp)];
      float ur = ar + br, ui = ai - bi;     // a + conj(b)
      float vr = ar - br, vi = -ai - bi;    // conj(a) - b
      float xr = ur*vr - ui*vi;
      float xi = ur*vi + ui*vr;
      prr[mm] = -xi * scale;                // * i
      pii[mm] =  xr * scale;
    }
    __syncthreads();
#pragma unroll
    for (int mm = 0; mm < 16; ++mm) {
      int pos = tid + (mm << 8);
      re[SW(pos)] = prr[mm];
      im[SW(pos)] = pii[mm];
    }
    __syncthreads();
  }

  // ---------- inverse DIT stages (q = 1, 4, 16, 64, 256) ----------
  for (int lq = 0; lq <= 8; lq += 2) {
    const int q = 1 << lq;
    const float cf = PI2 / (float)(q << 2);
#pragma unroll
    for (int mm = 0; mm < 4; ++mm) {
      int j = tid + (mm << 8);
      int p = j & (q - 1);
      int base = ((j >> lq) << (lq + 2)) + p;
      int i0 = SW(base), i1 = SW(base + q), i2 = SW(base + 2*q), i3 = SW(base + 3*q);
      float z0r = re[i0], z0i = im[i0];
      float x1r = re[i1], x1i = im[i1];
      float x2r = re[i2], x2i = im[i2];
      float x3r = re[i3], x3i = im[i3];
      float ang = cf * (float)p;
      float s1, c1;  __sincosf(ang, &s1, &c1);
      float c2 = c1*c1 - s1*s1, s2 = 2.f*c1*s1;
      float c3 = c1*c2 - s1*s2, s3 = c1*s2 + s1*c2;
      float u1r = x1r*c1 - x1i*s1, u1i = x1r*s1 + x1i*c1;
      float u2r = x2r*c2 - x2i*s2, u2i = x2r*s2 + x2i*c2;
      float u3r = x3r*c3 - x3i*s3, u3i = x3r*s3 + x3i*c3;
      float t0r = z0r + u2r, t0i = z0i + u2i;
      float t1r = z0r - u2r, t1i = z0i - u2i;
      float t2r = u1r + u3r, t2i = u1i + u3i;
      float t3r = u1r - u3r, t3i = u1i - u3i;
      re[i0] = t0r + t2r;  im[i0] = t0i + t2i;
      re[i1] = t1r - t3i;  im[i1] = t1i + t3r;   // t1 + i*t3
      re[i2] = t0r - t2r;  im[i2] = t0i - t2i;
      re[i3] = t1r + t3i;  im[i3] = t1i - t3r;   // t1 - i*t3
    }
    __syncthreads();
  }

  // ---------- final inverse stage (q=1024) -> Rxx real part in registers ----------
  float rr[16];
  {
    const float cf = PI2 / (float)FFT_N;
#pragma unroll
    for (int mm = 0; mm < 4; ++mm) {
      int j = tid + (mm << 8);
      int i0 = SW(j), i1 = SW(j + 1024), i2 = SW(j + 2048), i3 = SW(j + 3072);
      float z0r = re[i0], z0i = im[i0];
      float x1r = re[i1], x1i = im[i1];
      float x2r = re[i2], x2i = im[i2];
      float x3r = re[i3], x3i = im[i3];
      float ang = cf * (float)j;
      float s1, c1;  __sincosf(ang, &s1, &c1);
      float c2 = c1*c1 - s1*s1, s2 = 2.f*c1*s1;
      float c3 = c1*c2 - s1*s2, s3 = c1*s2 + s1*c2;
      float u1r = x1r*c1 - x1i*s1, u1i = x1r*s1 + x1i*c1;
      float u2r = x2r*c2 - x2i*s2;
      float u3r = x3r*c3 - x3i*s3, u3i = x3r*s3 + x3i*c3;
      float t0r = z0r + u2r;
      float t1r = z0r - u2r;
      float t2r = u1r + u3r;
      float t3i = u1i - u3i;
      rr[(mm << 2) | 0] = t0r + t2r;   // idx j
      rr[(mm << 2) | 1] = t1r - t3i;   // idx j+1024
      rr[(mm << 2) | 2] = t0r - t2r;   // idx j+2048
      rr[(mm << 2) | 3] = t1r + t3i;   // idx j+3072
    }
  }
  __syncthreads();   // all LDS reads done; re/im now free

  // ---------- stage V row into LDS (natural order, re[] reused) ----------
#pragma unroll
  for (int mm = 0; mm < 16; ++mm) {
    int g = tid + (mm << 8);
    re[g] = Vt[row + g];
  }
  // visibility to gather is guaranteed by the top-k barriers below

  // ---------- top-24: register scan + wave shuffle + 1 barrier/iter ----------
  float m0 = 0.f, esum = 0.f;     // live on thread 0 only
#pragma unroll 1
  for (int t = 0; t < TOPK; ++t) {
    float bv = -3e38f; int bn = 0;
#pragma unroll
    for (int cc = 0; cc < 4; ++cc)
#pragma unroll
      for (int mm = 0; mm < 4; ++mm) {       // ascending global index order
        float v = rr[(mm << 2) | cc];
        if (v > bv) { bv = v; bn = (mm << 2) | cc; }
      }
    int bi = tid + ((bn >> 2) << 8) + ((bn & 3) << 10);
#pragma unroll
    for (int off = 32; off; off >>= 1) {
      float ov = __shfl_xor(bv, off);
      int   oi = __shfl_xor(bi, off);
      if (ov > bv || (ov == bv && oi < bi)) { bv = ov; bi = oi; }
    }
    int par = t & 1;
    if ((tid & 63) == 0) { sv[par][tid >> 6] = bv; si[par][tid >> 6] = bi; }
    __syncthreads();
    float wv = sv[par][0]; int wi = si[par][0];
#pragma unroll
    for (int w = 1; w < 4; ++w) {
      float v2 = sv[par][w]; int i2 = si[par][w];
      if (v2 > wv || (v2 == wv && i2 < wi)) { wv = v2; wi = i2; }
    }
    if (tid == 0) {
      if (t == 0) m0 = wv;
      float e = __expf(wv - m0);
      esum += e;
      swk[t] = e; sik[t] = wi;
    }
    if ((wi & 255) == tid) {                 // owner clears the taken slot
      int n = (((wi >> 8) & 3) << 2) | ((wi >> 10) & 3);
#pragma unroll
      for (int z = 0; z < 16; ++z) if (z == n) rr[z] = -3e38f;
    }
  }
  if (tid == 0) sinv = 1.f / esum;
  __syncthreads();

  // ---------- gather: A[l] = (1/esum) * sum_t e_t * V[(l + i_t) & 4095] ----------
  float inv = sinv;
  float wkr[TOPK]; int ikr[TOPK];
#pragma unroll
  for (int t = 0; t < TOPK; ++t) { wkr[t] = swk[t]; ikr[t] = sik[t]; }
#pragma unroll
  for (int mm = 0; mm < 16; ++mm) {
    int j = tid + (mm << 8);
    float acc = 0.f;
#pragma unroll
    for (int t = 0; t < TOPK; ++t)
      acc += wkr[t] * re[(j + ikr[t]) & (FFT_N - 1)];
    At[row + j] = acc * inv;
  }
}

extern "C" void kernel_launch(void* const* d_in, const int* in_sizes, int n_in,
                              void* d_out, int out_size, void* d_ws, size_t ws_size,
                              hipStream_t stream) {
  const float* Q = (const float*)d_in[0];
  const float* K = (const float*)d_in[1];
  const float* V = (const float*)d_in[2];
  float* out = (float*)d_out;
  float* ws = (float*)d_ws;

  const int B = 16, L = 4096, D = 64;
  const size_t SLAB = (size_t)B * L * D;
  float* Qt = ws;
  float* Kt = ws + SLAB;
  float* Vt = ws + 2 * SLAB;
  float* At = Qt;   // alias: safe, each block reads its row fully before writing

  dim3 blk(256);
  transpose64<<<dim3(64, B), blk, 0, stream>>>(Q, Qt, L, D);
  transpose64<<<dim3(64, B), blk, 0, stream>>>(K, Kt, L, D);
  transpose64<<<dim3(64, B), blk, 0, stream>>>(V, Vt, L, D);

  corr_kernel<<<dim3(B * D), blk, 0, stream>>>(Qt, Kt, Vt, At);

  transpose64<<<dim3(64, B), blk, 0, stream>>>(At, out, D, L);
}

// Round 3
// 85.874 us; speedup vs baseline: 1.4532x; 1.2163x over previous
//
#include <hip/hip_runtime.h>

// AutoCorrelation attention — register-resident 3-level radix-16 FFT.
// B=16, L=4096, D=64, k=24.

#define FFT_N 4096
#define TOPK  24
#define PI2   6.28318530717958647692f
#define C16_1 0.92387953251128675613f   // cos(pi/8)
#define S16_1 0.38268343236508977173f   // sin(pi/8)
#define C16_2 0.70710678118654752440f   // cos(pi/4)

__device__ __forceinline__ float2 cmul(float2 a, float2 b) {
  return make_float2(a.x*b.x - a.y*b.y, a.x*b.y + a.y*b.x);
}

// 16-point DFT, natural order in and out. S=-1 forward, S=+1 inverse.
template<int S>
__device__ __forceinline__ void fft16(float2* x) {
  const float sg = (float)S;
  float2 y[16];
#pragma unroll
  for (int n2 = 0; n2 < 4; ++n2) {
    float2 a = x[n2], b = x[4+n2], c = x[8+n2], d = x[12+n2];
    float t0r=a.x+c.x, t0i=a.y+c.y, t1r=a.x-c.x, t1i=a.y-c.y;
    float t2r=b.x+d.x, t2i=b.y+d.y, t3r=b.x-d.x, t3i=b.y-d.y;
    y[n2*4+0] = make_float2(t0r+t2r, t0i+t2i);
    y[n2*4+2] = make_float2(t0r-t2r, t0i-t2i);
    y[n2*4+1] = make_float2(t1r - sg*t3i, t1i + sg*t3r);   // t1 + S*i*t3
    y[n2*4+3] = make_float2(t1r + sg*t3i, t1i - sg*t3r);   // t1 - S*i*t3
  }
  // y[n2*4+k1] *= w16^(S*n2*k1), compile-time constants
#define CTW(ii, cc, ss) { float2 v=y[ii]; y[ii]=make_float2(v.x*(cc)-v.y*(sg*(ss)), v.x*(sg*(ss))+v.y*(cc)); }
  CTW(5,  C16_1, S16_1)
  CTW(6,  C16_2, C16_2)
  CTW(7,  S16_1, C16_1)
  CTW(9,  C16_2, C16_2)
  { float2 v = y[10]; y[10] = make_float2(-sg*v.y, sg*v.x); }   // *S*i
  CTW(11, -C16_2, C16_2)
  CTW(13, S16_1, C16_1)
  CTW(14, -C16_2, C16_2)
  CTW(15, -C16_1, -S16_1)
#undef CTW
#pragma unroll
  for (int k1 = 0; k1 < 4; ++k1) {
    float2 a = y[k1], b = y[4+k1], c = y[8+k1], d = y[12+k1];
    float t0r=a.x+c.x, t0i=a.y+c.y, t1r=a.x-c.x, t1i=a.y-c.y;
    float t2r=b.x+d.x, t2i=b.y+d.y, t3r=b.x-d.x, t3i=b.y-d.y;
    x[k1+0]  = make_float2(t0r+t2r, t0i+t2i);
    x[k1+8]  = make_float2(t0r-t2r, t0i-t2i);
    x[k1+4]  = make_float2(t1r - sg*t3i, t1i + sg*t3r);
    x[k1+12] = make_float2(t1r + sg*t3i, t1i - sg*t3r);
  }
}

// x[k] *= w^k, w = e^{i*ang}, k=1..15 (recurrence)
__device__ __forceinline__ void twiddle_chain(float2* x, float ang) {
  float sb, cb; __sincosf(ang, &sb, &cb);
  float2 w = make_float2(cb, sb);
  float2 cw = w;
  x[1] = cmul(x[1], cw);
#pragma unroll
  for (int k = 2; k < 16; ++k) { cw = cmul(cw, w); x[k] = cmul(x[k], cw); }
}

__global__ __launch_bounds__(256) void transpose64(const float* __restrict__ in,
                                                   float* __restrict__ out,
                                                   int R, int C) {
  __shared__ float tile[64][65];
  int tiles_c = C >> 6;
  int tr = blockIdx.x / tiles_c;
  int tc = blockIdx.x - tr * tiles_c;
  const float* inb = in + (size_t)blockIdx.y * R * C;
  float* outb = out + (size_t)blockIdx.y * R * C;
  int tx = threadIdx.x & 63;
  int ty = threadIdx.x >> 6;
  int r0 = tr << 6, c0 = tc << 6;
#pragma unroll
  for (int i = 0; i < 16; ++i) {
    int r = (i << 2) + ty;
    tile[r][tx] = inb[(size_t)(r0 + r) * C + (c0 + tx)];
  }
  __syncthreads();
#pragma unroll
  for (int i = 0; i < 16; ++i) {
    int r = (i << 2) + ty;
    outb[(size_t)(c0 + r) * R + (r0 + tx)] = tile[tx][r];
  }
}

__global__ __launch_bounds__(256, 4) void corr_kernel(const float* __restrict__ Qt,
                                                      const float* __restrict__ Kt,
                                                      const float* __restrict__ Vt,
                                                      float* __restrict__ At) {
  __shared__ float2 Z[FFT_N];          // 32 KB, multi-purpose
  __shared__ float sv[2][4];
  __shared__ int   si[2][4];
  __shared__ float swk[TOPK];
  __shared__ int   sik[TOPK];
  __shared__ float sinv_s;

  const int tid = threadIdx.x;
  const size_t row = (size_t)blockIdx.x << 12;

  float2 x[16];

  // ======== forward FFT of z = q + i*k ========
  // level 1: thread t owns x[n1*256 + t]
#pragma unroll
  for (int n1 = 0; n1 < 16; ++n1)
    x[n1] = make_float2(Qt[row + (n1 << 8) + tid], Kt[row + (n1 << 8) + tid]);
  fft16<-1>(x);
  twiddle_chain(x, -PI2 * (float)tid / 4096.f);   // w4096^{-k1*t}
  // transpose 1: write [k1][t]
#pragma unroll
  for (int k = 0; k < 16; ++k) Z[(k << 8) + tid] = x[k];
  __syncthreads();
  {
    // level 2: thread role (k1, b) = (tid>>4, tid&15), gather stride-16 over a
    const int k1 = tid >> 4, b = tid & 15;
#pragma unroll
    for (int a = 0; a < 16; ++a) x[a] = Z[(k1 << 8) + (a << 4) + b];
    fft16<-1>(x);
    twiddle_chain(x, -PI2 * (float)b / 256.f);    // w256^{-b*c}
    __syncthreads();
    // transpose 2: [k1][c][b^c] (XOR swizzle for bank spread)
#pragma unroll
    for (int cc = 0; cc < 16; ++cc) Z[(k1 << 8) + (cc << 4) + (b ^ cc)] = x[cc];
  }
  __syncthreads();
  {
    // level 3: thread role (k1, c), gather over b
    const int k1 = tid >> 4, c = tid & 15;
#pragma unroll
    for (int bb = 0; bb < 16; ++bb) x[bb] = Z[(k1 << 8) + (c << 4) + (bb ^ c)];
    fft16<-1>(x);                                  // x[d] = X[k1 + 16c + 256d]
    __syncthreads();
    // write spectrum swizzled-natural: loc(f) = f ^ ((f>>4)&15) = f ^ c
    const int bf = k1 + (c << 4);
#pragma unroll
    for (int d = 0; d < 16; ++d) Z[(bf ^ c) + (d << 8)] = x[d];
  }
  __syncthreads();

  // ======== pointwise P = Qf*conj(Kf) * (1/4N), becomes inverse level-1 input ========
  {
    const float scale = 0.25f / 4096.f;
    const int x1 = tid >> 4;
#pragma unroll
    for (int f1 = 0; f1 < 16; ++f1) {
      int f  = (f1 << 8) + tid;
      int fp = (4096 - f) & 4095;
      float2 A  = Z[f ^ x1];
      float2 Bv = Z[fp ^ ((fp >> 4) & 15)];
      float ur = A.x + Bv.x, ui = A.y - Bv.y;     // a + conj(b)
      float vr = A.x - Bv.x, vi = -A.y - Bv.y;    // conj(a) - b
      float xr = ur*vr - ui*vi, xi = ur*vi + ui*vr;
      x[f1] = make_float2(-xi * scale, xr * scale);   // *i
    }
  }

  // ======== inverse FFT (mirror, S=+1) ========
  fft16<1>(x);
  twiddle_chain(x, PI2 * (float)tid / 4096.f);
  __syncthreads();                                 // pointwise reads done
#pragma unroll
  for (int k = 0; k < 16; ++k) Z[(k << 8) + tid] = x[k];
  __syncthreads();
  {
    const int k1 = tid >> 4, b = tid & 15;
#pragma unroll
    for (int a = 0; a < 16; ++a) x[a] = Z[(k1 << 8) + (a << 4) + b];
    fft16<1>(x);
    twiddle_chain(x, PI2 * (float)b / 256.f);
    __syncthreads();
#pragma unroll
    for (int cc = 0; cc < 16; ++cc) Z[(k1 << 8) + (cc << 4) + (b ^ cc)] = x[cc];
  }
  __syncthreads();
  float rr[16];
  {
    const int k1 = tid >> 4, c = tid & 15;
#pragma unroll
    for (int bb = 0; bb < 16; ++bb) x[bb] = Z[(k1 << 8) + (c << 4) + (bb ^ c)];
    fft16<1>(x);
#pragma unroll
    for (int d = 0; d < 16; ++d) rr[d] = x[d].x;   // Rxx[k1 + 16c + 256d]
  }
  __syncthreads();                                 // all Z reads done

  // ======== stage V dual shifted copies: V0[n]=V[n], V1[n]=V[(n+1)%N] ========
  float* Vf = (float*)Z;
#pragma unroll
  for (int mm = 0; mm < 4; ++mm) {
    int n0 = (tid << 2) + (mm << 10);
    float4 v = *(const float4*)&Vt[row + n0];
    *(float4*)&Vf[n0] = v;
    Vf[4096 + ((n0 - 1) & 4095)] = v.x;
    Vf[4096 + n0]     = v.y;
    Vf[4096 + n0 + 1] = v.z;
    Vf[4096 + n0 + 2] = v.w;
  }
  // (visibility to gather via the top-k barriers below)

  // ======== top-24, incremental local max ========
  float lmax = -3e38f; int lj = 0;
#pragma unroll
  for (int j = 0; j < 16; ++j) if (rr[j] > lmax) { lmax = rr[j]; lj = j; }
  const int tbase = (tid >> 4) + ((tid & 15) << 4);  // tau low-8 for this thread
  float m0 = 0.f, esum = 0.f;
#pragma unroll 1
  for (int t = 0; t < TOPK; ++t) {
    float bv = lmax; int bi = tbase + (lj << 8);
#pragma unroll
    for (int off = 32; off; off >>= 1) {
      float ov = __shfl_xor(bv, off);
      int   oi = __shfl_xor(bi, off);
      if (ov > bv || (ov == bv && oi < bi)) { bv = ov; bi = oi; }
    }
    int par = t & 1;
    if ((tid & 63) == 0) { sv[par][tid >> 6] = bv; si[par][tid >> 6] = bi; }
    __syncthreads();
    float wv = sv[par][0]; int wi = si[par][0];
#pragma unroll
    for (int w = 1; w < 4; ++w) {
      float v2 = sv[par][w]; int i2 = si[par][w];
      if (v2 > wv || (v2 == wv && i2 < wi)) { wv = v2; wi = i2; }
    }
    if (tid == 0) {
      if (t == 0) m0 = wv;
      float e = __expf(wv - m0);
      esum += e;
      swk[t] = e; sik[t] = wi;
    }
    if ((wi & 255) == tbase) {       // winner thread: clear slot, rescan
      int wj = wi >> 8;
#pragma unroll
      for (int z = 0; z < 16; ++z) if (z == wj) rr[z] = -3e38f;
      lmax = -3e38f; lj = 0;
#pragma unroll
      for (int z = 0; z < 16; ++z) if (rr[z] > lmax) { lmax = rr[z]; lj = z; }
    }
  }
  if (tid == 0) sinv_s = 1.f / esum;
  __syncthreads();

  // ======== gather: A[l] = inv * sum_t e_t * V[(l + i_t) % N], float2 pairs ========
  const float inv = sinv_s;
  float wk[TOPK]; int iofs[TOPK], ipg[TOPK];
#pragma unroll
  for (int t = 0; t < TOPK; ++t) {
    wk[t] = swk[t];
    int ik = sik[t];
    ipg[t]  = (ik & 1) << 12;        // which shifted copy
    iofs[t] = ik & ~1;               // even base offset
  }
#pragma unroll
  for (int mm = 0; mm < 8; ++mm) {
    int l = (tid << 1) + (mm << 9);
    float accx = 0.f, accy = 0.f;
#pragma unroll
    for (int t = 0; t < TOPK; ++t) {
      int e = (l + iofs[t]) & 4095;
      float2 vv = *(float2*)&Vf[ipg[t] + e];
      accx += wk[t] * vv.x;
      accy += wk[t] * vv.y;
    }
    float2 res = make_float2(accx * inv, accy * inv);
    *(float2*)&At[row + l] = res;
  }
}

extern "C" void kernel_launch(void* const* d_in, const int* in_sizes, int n_in,
                              void* d_out, int out_size, void* d_ws, size_t ws_size,
                              hipStream_t stream) {
  const float* Q = (const float*)d_in[0];
  const float* K = (const float*)d_in[1];
  const float* V = (const float*)d_in[2];
  float* out = (float*)d_out;
  float* ws = (float*)d_ws;

  const int B = 16, L = 4096, D = 64;
  const size_t SLAB = (size_t)B * L * D;
  float* Qt = ws;
  float* Kt = ws + SLAB;
  float* Vt = ws + 2 * SLAB;
  float* At = Qt;   // alias: safe, each block reads its row fully before writing

  dim3 blk(256);
  transpose64<<<dim3(64, B), blk, 0, stream>>>(Q, Qt, L, D);
  transpose64<<<dim3(64, B), blk, 0, stream>>>(K, Kt, L, D);
  transpose64<<<dim3(64, B), blk, 0, stream>>>(V, Vt, L, D);

  corr_kernel<<<dim3(B * D), blk, 0, stream>>>(Qt, Kt, Vt, At);

  transpose64<<<dim3(64, B), blk, 0, stream>>>(At, out, D, L);
}

// Round 4
// 74.316 us; speedup vs baseline: 1.6792x; 1.1555x over previous
//
#include <hip/hip_runtime.h>

// AutoCorrelation attention — register-resident 3-level radix-16 FFT.
// B=16, L=4096, D=64, k=24.
// This round: single-wave top-k (candidate pruning), fused QK transpose,
// prefetched V staging, twiddle product tree. FFT core unchanged from R3.

#define FFT_N 4096
#define TOPK  24
#define PI2   6.28318530717958647692f
#define C16_1 0.92387953251128675613f   // cos(pi/8)
#define S16_1 0.38268343236508977173f   // sin(pi/8)
#define C16_2 0.70710678118654752440f   // cos(pi/4)

__device__ __forceinline__ float2 cmul(float2 a, float2 b) {
  return make_float2(a.x*b.x - a.y*b.y, a.x*b.y + a.y*b.x);
}

// 16-point DFT, natural order in and out. S=-1 forward, S=+1 inverse.
template<int S>
__device__ __forceinline__ void fft16(float2* x) {
  const float sg = (float)S;
  float2 y[16];
#pragma unroll
  for (int n2 = 0; n2 < 4; ++n2) {
    float2 a = x[n2], b = x[4+n2], c = x[8+n2], d = x[12+n2];
    float t0r=a.x+c.x, t0i=a.y+c.y, t1r=a.x-c.x, t1i=a.y-c.y;
    float t2r=b.x+d.x, t2i=b.y+d.y, t3r=b.x-d.x, t3i=b.y-d.y;
    y[n2*4+0] = make_float2(t0r+t2r, t0i+t2i);
    y[n2*4+2] = make_float2(t0r-t2r, t0i-t2i);
    y[n2*4+1] = make_float2(t1r - sg*t3i, t1i + sg*t3r);
    y[n2*4+3] = make_float2(t1r + sg*t3i, t1i - sg*t3r);
  }
#define CTW(ii, cc, ss) { float2 v=y[ii]; y[ii]=make_float2(v.x*(cc)-v.y*(sg*(ss)), v.x*(sg*(ss))+v.y*(cc)); }
  CTW(5,  C16_1, S16_1)
  CTW(6,  C16_2, C16_2)
  CTW(7,  S16_1, C16_1)
  CTW(9,  C16_2, C16_2)
  { float2 v = y[10]; y[10] = make_float2(-sg*v.y, sg*v.x); }
  CTW(11, -C16_2, C16_2)
  CTW(13, S16_1, C16_1)
  CTW(14, -C16_2, C16_2)
  CTW(15, -C16_1, -S16_1)
#undef CTW
#pragma unroll
  for (int k1 = 0; k1 < 4; ++k1) {
    float2 a = y[k1], b = y[4+k1], c = y[8+k1], d = y[12+k1];
    float t0r=a.x+c.x, t0i=a.y+c.y, t1r=a.x-c.x, t1i=a.y-c.y;
    float t2r=b.x+d.x, t2i=b.y+d.y, t3r=b.x-d.x, t3i=b.y-d.y;
    x[k1+0]  = make_float2(t0r+t2r, t0i+t2i);
    x[k1+8]  = make_float2(t0r-t2r, t0i-t2i);
    x[k1+4]  = make_float2(t1r - sg*t3i, t1i + sg*t3r);
    x[k1+12] = make_float2(t1r + sg*t3i, t1i - sg*t3r);
  }
}

// x[k] *= w^k, k=1..15; powers built as a depth-4 product tree (ILP).
__device__ __forceinline__ void twiddle_chain(float2* x, float ang) {
  float sb, cb; __sincosf(ang, &sb, &cb);
  float2 w1 = make_float2(cb, sb);
  float2 w2 = cmul(w1,w1), w3 = cmul(w1,w2);
  float2 w4 = cmul(w2,w2), w5 = cmul(w2,w3), w6 = cmul(w3,w3), w7 = cmul(w3,w4);
  float2 w8 = cmul(w4,w4), w9 = cmul(w4,w5), w10 = cmul(w5,w5), w11 = cmul(w5,w6);
  float2 w12 = cmul(w6,w6), w13 = cmul(w6,w7), w14 = cmul(w7,w7), w15 = cmul(w7,w8);
  x[1]=cmul(x[1],w1);   x[2]=cmul(x[2],w2);   x[3]=cmul(x[3],w3);
  x[4]=cmul(x[4],w4);   x[5]=cmul(x[5],w5);   x[6]=cmul(x[6],w6);
  x[7]=cmul(x[7],w7);   x[8]=cmul(x[8],w8);   x[9]=cmul(x[9],w9);
  x[10]=cmul(x[10],w10); x[11]=cmul(x[11],w11); x[12]=cmul(x[12],w12);
  x[13]=cmul(x[13],w13); x[14]=cmul(x[14],w14); x[15]=cmul(x[15],w15);
}

// Q,K [B,L,D] -> interleaved float2 (q,k) in [B,D,L]
__global__ __launch_bounds__(256) void transposeQK(const float* __restrict__ Q,
                                                   const float* __restrict__ K,
                                                   float2* __restrict__ ZQK) {
  __shared__ float tq[64][65];
  __shared__ float tk[64][65];
  const int b = blockIdx.y;
  const int t0 = blockIdx.x << 6;
  const float* Qb = Q + ((size_t)b << 18);
  const float* Kb = K + ((size_t)b << 18);
  int tx = threadIdx.x & 63, ty = threadIdx.x >> 6;
#pragma unroll
  for (int i = 0; i < 16; ++i) {
    int r = (i << 2) + ty;
    tq[r][tx] = Qb[(size_t)(t0 + r) * 64 + tx];
    tk[r][tx] = Kb[(size_t)(t0 + r) * 64 + tx];
  }
  __syncthreads();
  float2* outb = ZQK + ((size_t)b << 18);
#pragma unroll
  for (int i = 0; i < 16; ++i) {
    int d = (i << 2) + ty;
    outb[(size_t)d * 4096 + t0 + tx] = make_float2(tq[tx][d], tk[tx][d]);
  }
}

__global__ __launch_bounds__(256) void transpose64(const float* __restrict__ in,
                                                   float* __restrict__ out,
                                                   int R, int C) {
  __shared__ float tile[64][65];
  int tiles_c = C >> 6;
  int tr = blockIdx.x / tiles_c;
  int tc = blockIdx.x - tr * tiles_c;
  const float* inb = in + (size_t)blockIdx.y * R * C;
  float* outb = out + (size_t)blockIdx.y * R * C;
  int tx = threadIdx.x & 63;
  int ty = threadIdx.x >> 6;
  int r0 = tr << 6, c0 = tc << 6;
#pragma unroll
  for (int i = 0; i < 16; ++i) {
    int r = (i << 2) + ty;
    tile[r][tx] = inb[(size_t)(r0 + r) * C + (c0 + tx)];
  }
  __syncthreads();
#pragma unroll
  for (int i = 0; i < 16; ++i) {
    int r = (i << 2) + ty;
    outb[(size_t)(c0 + r) * R + (r0 + tx)] = tile[tx][r];
  }
}

__global__ __launch_bounds__(256, 4) void corr_kernel(const float2* __restrict__ ZQK,
                                                      const float* __restrict__ Vt,
                                                      float* __restrict__ At) {
  __shared__ float2 Z[FFT_N];          // 32 KB, multi-purpose
  __shared__ float swk[TOPK];
  __shared__ int   sik[TOPK];
  __shared__ float sinv_s;

  const int tid = threadIdx.x;
  const size_t row  = (size_t)blockIdx.x << 12;   // float index into Vt/At
  const size_t rowz = (size_t)blockIdx.x << 12;   // float2 index into ZQK

  float2 x[16];

  // ======== forward FFT of z = q + i*k ========
#pragma unroll
  for (int n1 = 0; n1 < 16; ++n1)
    x[n1] = ZQK[rowz + (n1 << 8) + tid];
  fft16<-1>(x);
  twiddle_chain(x, -PI2 * (float)tid / 4096.f);
#pragma unroll
  for (int k = 0; k < 16; ++k) Z[(k << 8) + tid] = x[k];
  __syncthreads();
  {
    const int k1 = tid >> 4, b = tid & 15;
#pragma unroll
    for (int a = 0; a < 16; ++a) x[a] = Z[(k1 << 8) + (a << 4) + b];
    fft16<-1>(x);
    twiddle_chain(x, -PI2 * (float)b / 256.f);
    __syncthreads();
#pragma unroll
    for (int cc = 0; cc < 16; ++cc) Z[(k1 << 8) + (cc << 4) + (b ^ cc)] = x[cc];
  }
  __syncthreads();
  {
    const int k1 = tid >> 4, c = tid & 15;
#pragma unroll
    for (int bb = 0; bb < 16; ++bb) x[bb] = Z[(k1 << 8) + (c << 4) + (bb ^ c)];
    fft16<-1>(x);
    __syncthreads();
    const int bf = k1 + (c << 4);
#pragma unroll
    for (int d = 0; d < 16; ++d) Z[(bf ^ c) + (d << 8)] = x[d];
  }
  __syncthreads();

  // ======== pointwise P = Qf*conj(Kf) * (1/4N) ========
  {
    const float scale = 0.25f / 4096.f;
    const int x1 = tid >> 4;
#pragma unroll
    for (int f1 = 0; f1 < 16; ++f1) {
      int f  = (f1 << 8) + tid;
      int fp = (4096 - f) & 4095;
      float2 A  = Z[f ^ x1];
      float2 Bv = Z[fp ^ ((fp >> 4) & 15)];
      float ur = A.x + Bv.x, ui = A.y - Bv.y;
      float vr = A.x - Bv.x, vi = -A.y - Bv.y;
      float xr = ur*vr - ui*vi, xi = ur*vi + ui*vr;
      x[f1] = make_float2(-xi * scale, xr * scale);
    }
  }

  // prefetch V row into registers (latency hidden under inverse FFT)
  float4 v4s[4];
#pragma unroll
  for (int mm = 0; mm < 4; ++mm)
    v4s[mm] = *(const float4*)&Vt[row + (tid << 2) + (mm << 10)];

  // ======== inverse FFT ========
  fft16<1>(x);
  twiddle_chain(x, PI2 * (float)tid / 4096.f);
  __syncthreads();
#pragma unroll
  for (int k = 0; k < 16; ++k) Z[(k << 8) + tid] = x[k];
  __syncthreads();
  {
    const int k1 = tid >> 4, b = tid & 15;
#pragma unroll
    for (int a = 0; a < 16; ++a) x[a] = Z[(k1 << 8) + (a << 4) + b];
    fft16<1>(x);
    twiddle_chain(x, PI2 * (float)b / 256.f);
    __syncthreads();
#pragma unroll
    for (int cc = 0; cc < 16; ++cc) Z[(k1 << 8) + (cc << 4) + (b ^ cc)] = x[cc];
  }
  __syncthreads();
  float rr[16];
  {
    const int k1 = tid >> 4, c = tid & 15;
#pragma unroll
    for (int bb = 0; bb < 16; ++bb) x[bb] = Z[(k1 << 8) + (c << 4) + (bb ^ c)];
    fft16<1>(x);
#pragma unroll
    for (int d = 0; d < 16; ++d) rr[d] = x[d].x;   // Rxx[k1 + 16c + 256d]
  }
  __syncthreads();                                 // Z free

  // ======== stage V0 copy + local top-5 candidates ========
  float* Vf = (float*)Z;                           // floats [0..8191]
#pragma unroll
  for (int mm = 0; mm < 4; ++mm) {
    int n0 = (tid << 2) + (mm << 10);
    *(float4*)&Vf[n0] = v4s[mm];                   // V0: floats [0..4095]
  }

  const int tbase = (tid >> 4) + ((tid & 15) << 4);
  {
    float c0v=-3e38f,c1v=-3e38f,c2v=-3e38f,c3v=-3e38f,c4v=-3e38f;
    int   c0i=0x7fffffff,c1i=0x7fffffff,c2i=0x7fffffff,c3i=0x7fffffff,c4i=0x7fffffff;
#pragma unroll
    for (int d = 0; d < 16; ++d) {
      float v = rr[d];
      int  gi = tbase + (d << 8);
      bool g0 = v > c0v, g1 = v > c1v, g2 = v > c2v, g3 = v > c3v, g4 = v > c4v;
      c4v = g3 ? c3v : (g4 ? v : c4v);  c4i = g3 ? c3i : (g4 ? gi : c4i);
      c3v = g2 ? c2v : (g3 ? v : c3v);  c3i = g2 ? c2i : (g3 ? gi : c3i);
      c2v = g1 ? c1v : (g2 ? v : c2v);  c2i = g1 ? c1i : (g2 ? gi : c2i);
      c1v = g0 ? c0v : (g1 ? v : c1v);  c1i = g0 ? c0i : (g1 ? gi : c1i);
      c0v = g0 ? v : c0v;               c0i = g0 ? gi : c0i;
    }
    // candidates in V1 region (floats [4096..6655]), written before V1 staging
    const int cb = 2048 + tid * 5;
    Z[cb+0] = make_float2(c0v, __int_as_float(c0i));
    Z[cb+1] = make_float2(c1v, __int_as_float(c1i));
    Z[cb+2] = make_float2(c2v, __int_as_float(c2i));
    Z[cb+3] = make_float2(c3v, __int_as_float(c3i));
    Z[cb+4] = make_float2(c4v, __int_as_float(c4i));
  }
  __syncthreads();   // B1: candidates + V0 visible

  // ======== wave-0 only: top-24 via 4-run sorted merge ========
  if (tid < 64) {
    const int cb = 2048 + tid * 20;     // this lane's 4 sorted runs of 5
    int p0 = 0, p1 = 0, p2 = 0, p3 = 0;
    float m0s = 0.f, esum = 0.f;
#pragma unroll 1
    for (int t = 0; t < TOPK; ++t) {
      float2 h0 = Z[cb + 0*5 + (p0 < 5 ? p0 : 4)];
      float2 h1 = Z[cb + 1*5 + (p1 < 5 ? p1 : 4)];
      float2 h2 = Z[cb + 2*5 + (p2 < 5 ? p2 : 4)];
      float2 h3 = Z[cb + 3*5 + (p3 < 5 ? p3 : 4)];
      float hv0 = (p0 < 5) ? h0.x : -3e38f;  int hi0 = __float_as_int(h0.y);
      float hv1 = (p1 < 5) ? h1.x : -3e38f;  int hi1 = __float_as_int(h1.y);
      float hv2 = (p2 < 5) ? h2.x : -3e38f;  int hi2 = __float_as_int(h2.y);
      float hv3 = (p3 < 5) ? h3.x : -3e38f;  int hi3 = __float_as_int(h3.y);
      float bv = hv0; int bi = hi0;
      if (hv1 > bv || (hv1 == bv && hi1 < bi)) { bv = hv1; bi = hi1; }
      if (hv2 > bv || (hv2 == bv && hi2 < bi)) { bv = hv2; bi = hi2; }
      if (hv3 > bv || (hv3 == bv && hi3 < bi)) { bv = hv3; bi = hi3; }
#pragma unroll
      for (int off = 32; off; off >>= 1) {
        float ov = __shfl_xor(bv, off);
        int   oi = __shfl_xor(bi, off);
        if (ov > bv || (ov == bv && oi < bi)) { bv = ov; bi = oi; }
      }
      p0 += (hi0 == bi) ? 1 : 0;
      p1 += (hi1 == bi) ? 1 : 0;
      p2 += (hi2 == bi) ? 1 : 0;
      p3 += (hi3 == bi) ? 1 : 0;
      if (t == 0) m0s = bv;
      float e = __expf(bv - m0s);
      esum += e;
      if (tid == 0) { swk[t] = e; sik[t] = bi; }
    }
    if (tid == 0) sinv_s = 1.f / esum;
  }
  __syncthreads();   // B2: selection done; cand area dead

  // ======== stage V1 shifted copy (overwrites candidate area) ========
#pragma unroll
  for (int mm = 0; mm < 4; ++mm) {
    int n0 = (tid << 2) + (mm << 10);
    float4 v = v4s[mm];
    Vf[4096 + ((n0 - 1) & 4095)] = v.x;
    Vf[4096 + n0]     = v.y;
    Vf[4096 + n0 + 1] = v.z;
    Vf[4096 + n0 + 2] = v.w;
  }
  __syncthreads();   // B3

  // ======== gather: A[l] = inv * sum_t e_t * V[(l + i_t) % N] ========
  const float inv = sinv_s;
  float wk[TOPK]; int iofs[TOPK], ipg[TOPK];
#pragma unroll
  for (int t = 0; t < TOPK; ++t) {
    wk[t] = swk[t];
    int ik = sik[t];
    ipg[t]  = (ik & 1) << 12;
    iofs[t] = ik & ~1;
  }
#pragma unroll
  for (int mm = 0; mm < 8; ++mm) {
    int l = (tid << 1) + (mm << 9);
    float accx = 0.f, accy = 0.f;
#pragma unroll
    for (int t = 0; t < TOPK; ++t) {
      int e = (l + iofs[t]) & 4095;
      float2 vv = *(float2*)&Vf[ipg[t] + e];
      accx += wk[t] * vv.x;
      accy += wk[t] * vv.y;
    }
    *(float2*)&At[row + l] = make_float2(accx * inv, accy * inv);
  }
}

extern "C" void kernel_launch(void* const* d_in, const int* in_sizes, int n_in,
                              void* d_out, int out_size, void* d_ws, size_t ws_size,
                              hipStream_t stream) {
  const float* Q = (const float*)d_in[0];
  const float* K = (const float*)d_in[1];
  const float* V = (const float*)d_in[2];
  float* out = (float*)d_out;
  float* wsf = (float*)d_ws;

  const int B = 16;
  const size_t SLAB = (size_t)4194304;       // B*L*D floats
  float2* ZQK = (float2*)wsf;                // 2*SLAB floats (33.5 MB)
  float*  Vt  = wsf + 2 * SLAB;
  float*  At  = Vt;   // alias: block i reads Vt row i (to regs) before writing At row i

  dim3 blk(256);
  transposeQK<<<dim3(64, B), blk, 0, stream>>>(Q, K, ZQK);
  transpose64<<<dim3(64, B), blk, 0, stream>>>(V, Vt, 4096, 64);

  corr_kernel<<<dim3(B * 64), blk, 0, stream>>>(ZQK, Vt, At);

  transpose64<<<dim3(64, B), blk, 0, stream>>>(At, out, 64, 4096);
}

// Round 5
// 74.288 us; speedup vs baseline: 1.6798x; 1.0004x over previous
//
#include <hip/hip_runtime.h>

// AutoCorrelation attention — register-resident 3-level radix-16 FFT.
// B=16, L=4096, D=64, k=24.
// R5: LDS trimmed to exactly 32 KiB (5 blocks/CU), top-k pack broadcast via
// Z scratch corner + registers, merge-read bank-conflict fix.

#define FFT_N 4096
#define TOPK  24
#define PI2   6.28318530717958647692f
#define C16_1 0.92387953251128675613f   // cos(pi/8)
#define S16_1 0.38268343236508977173f   // sin(pi/8)
#define C16_2 0.70710678118654752440f   // cos(pi/4)

__device__ __forceinline__ float2 cmul(float2 a, float2 b) {
  return make_float2(a.x*b.x - a.y*b.y, a.x*b.y + a.y*b.x);
}

// 16-point DFT, natural order in and out. S=-1 forward, S=+1 inverse.
template<int S>
__device__ __forceinline__ void fft16(float2* x) {
  const float sg = (float)S;
  float2 y[16];
#pragma unroll
  for (int n2 = 0; n2 < 4; ++n2) {
    float2 a = x[n2], b = x[4+n2], c = x[8+n2], d = x[12+n2];
    float t0r=a.x+c.x, t0i=a.y+c.y, t1r=a.x-c.x, t1i=a.y-c.y;
    float t2r=b.x+d.x, t2i=b.y+d.y, t3r=b.x-d.x, t3i=b.y-d.y;
    y[n2*4+0] = make_float2(t0r+t2r, t0i+t2i);
    y[n2*4+2] = make_float2(t0r-t2r, t0i-t2i);
    y[n2*4+1] = make_float2(t1r - sg*t3i, t1i + sg*t3r);
    y[n2*4+3] = make_float2(t1r + sg*t3i, t1i - sg*t3r);
  }
#define CTW(ii, cc, ss) { float2 v=y[ii]; y[ii]=make_float2(v.x*(cc)-v.y*(sg*(ss)), v.x*(sg*(ss))+v.y*(cc)); }
  CTW(5,  C16_1, S16_1)
  CTW(6,  C16_2, C16_2)
  CTW(7,  S16_1, C16_1)
  CTW(9,  C16_2, C16_2)
  { float2 v = y[10]; y[10] = make_float2(-sg*v.y, sg*v.x); }
  CTW(11, -C16_2, C16_2)
  CTW(13, S16_1, C16_1)
  CTW(14, -C16_2, C16_2)
  CTW(15, -C16_1, -S16_1)
#undef CTW
#pragma unroll
  for (int k1 = 0; k1 < 4; ++k1) {
    float2 a = y[k1], b = y[4+k1], c = y[8+k1], d = y[12+k1];
    float t0r=a.x+c.x, t0i=a.y+c.y, t1r=a.x-c.x, t1i=a.y-c.y;
    float t2r=b.x+d.x, t2i=b.y+d.y, t3r=b.x-d.x, t3i=b.y-d.y;
    x[k1+0]  = make_float2(t0r+t2r, t0i+t2i);
    x[k1+8]  = make_float2(t0r-t2r, t0i-t2i);
    x[k1+4]  = make_float2(t1r - sg*t3i, t1i + sg*t3r);
    x[k1+12] = make_float2(t1r + sg*t3i, t1i - sg*t3r);
  }
}

// x[k] *= w^k, k=1..15; powers built as a depth-4 product tree (ILP).
__device__ __forceinline__ void twiddle_chain(float2* x, float ang) {
  float sb, cb; __sincosf(ang, &sb, &cb);
  float2 w1 = make_float2(cb, sb);
  float2 w2 = cmul(w1,w1), w3 = cmul(w1,w2);
  float2 w4 = cmul(w2,w2), w5 = cmul(w2,w3), w6 = cmul(w3,w3), w7 = cmul(w3,w4);
  float2 w8 = cmul(w4,w4), w9 = cmul(w4,w5), w10 = cmul(w5,w5), w11 = cmul(w5,w6);
  float2 w12 = cmul(w6,w6), w13 = cmul(w6,w7), w14 = cmul(w7,w7), w15 = cmul(w7,w8);
  x[1]=cmul(x[1],w1);   x[2]=cmul(x[2],w2);   x[3]=cmul(x[3],w3);
  x[4]=cmul(x[4],w4);   x[5]=cmul(x[5],w5);   x[6]=cmul(x[6],w6);
  x[7]=cmul(x[7],w7);   x[8]=cmul(x[8],w8);   x[9]=cmul(x[9],w9);
  x[10]=cmul(x[10],w10); x[11]=cmul(x[11],w11); x[12]=cmul(x[12],w12);
  x[13]=cmul(x[13],w13); x[14]=cmul(x[14],w14); x[15]=cmul(x[15],w15);
}

// Q,K [B,L,D] -> interleaved float2 (q,k) in [B,D,L]
__global__ __launch_bounds__(256) void transposeQK(const float* __restrict__ Q,
                                                   const float* __restrict__ K,
                                                   float2* __restrict__ ZQK) {
  __shared__ float tq[64][65];
  __shared__ float tk[64][65];
  const int b = blockIdx.y;
  const int t0 = blockIdx.x << 6;
  const float* Qb = Q + ((size_t)b << 18);
  const float* Kb = K + ((size_t)b << 18);
  int tx = threadIdx.x & 63, ty = threadIdx.x >> 6;
#pragma unroll
  for (int i = 0; i < 16; ++i) {
    int r = (i << 2) + ty;
    tq[r][tx] = Qb[(size_t)(t0 + r) * 64 + tx];
    tk[r][tx] = Kb[(size_t)(t0 + r) * 64 + tx];
  }
  __syncthreads();
  float2* outb = ZQK + ((size_t)b << 18);
#pragma unroll
  for (int i = 0; i < 16; ++i) {
    int d = (i << 2) + ty;
    outb[(size_t)d * 4096 + t0 + tx] = make_float2(tq[tx][d], tk[tx][d]);
  }
}

__global__ __launch_bounds__(256) void transpose64(const float* __restrict__ in,
                                                   float* __restrict__ out,
                                                   int R, int C) {
  __shared__ float tile[64][65];
  int tiles_c = C >> 6;
  int tr = blockIdx.x / tiles_c;
  int tc = blockIdx.x - tr * tiles_c;
  const float* inb = in + (size_t)blockIdx.y * R * C;
  float* outb = out + (size_t)blockIdx.y * R * C;
  int tx = threadIdx.x & 63;
  int ty = threadIdx.x >> 6;
  int r0 = tr << 6, c0 = tc << 6;
#pragma unroll
  for (int i = 0; i < 16; ++i) {
    int r = (i << 2) + ty;
    tile[r][tx] = inb[(size_t)(r0 + r) * C + (c0 + tx)];
  }
  __syncthreads();
#pragma unroll
  for (int i = 0; i < 16; ++i) {
    int r = (i << 2) + ty;
    outb[(size_t)(c0 + r) * R + (r0 + tx)] = tile[tx][r];
  }
}

__global__ __launch_bounds__(256, 5) void corr_kernel(const float2* __restrict__ ZQK,
                                                      const float* __restrict__ Vt,
                                                      float* __restrict__ At) {
  __shared__ float2 Z[FFT_N];          // exactly 32 KiB — the ONLY shared array

  const int tid = threadIdx.x;
  const size_t row  = (size_t)blockIdx.x << 12;   // float index into Vt/At
  const size_t rowz = (size_t)blockIdx.x << 12;   // float2 index into ZQK

  float2 x[16];

  // ======== forward FFT of z = q + i*k ========
#pragma unroll
  for (int n1 = 0; n1 < 16; ++n1)
    x[n1] = ZQK[rowz + (n1 << 8) + tid];
  fft16<-1>(x);
  twiddle_chain(x, -PI2 * (float)tid / 4096.f);
#pragma unroll
  for (int k = 0; k < 16; ++k) Z[(k << 8) + tid] = x[k];
  __syncthreads();
  {
    const int k1 = tid >> 4, b = tid & 15;
#pragma unroll
    for (int a = 0; a < 16; ++a) x[a] = Z[(k1 << 8) + (a << 4) + b];
    fft16<-1>(x);
    twiddle_chain(x, -PI2 * (float)b / 256.f);
    __syncthreads();
#pragma unroll
    for (int cc = 0; cc < 16; ++cc) Z[(k1 << 8) + (cc << 4) + (b ^ cc)] = x[cc];
  }
  __syncthreads();
  {
    const int k1 = tid >> 4, c = tid & 15;
#pragma unroll
    for (int bb = 0; bb < 16; ++bb) x[bb] = Z[(k1 << 8) + (c << 4) + (bb ^ c)];
    fft16<-1>(x);
    __syncthreads();
    const int bf = k1 + (c << 4);
#pragma unroll
    for (int d = 0; d < 16; ++d) Z[(bf ^ c) + (d << 8)] = x[d];
  }
  __syncthreads();

  // ======== pointwise P = Qf*conj(Kf) * (1/4N) ========
  {
    const float scale = 0.25f / 4096.f;
    const int x1 = tid >> 4;
#pragma unroll
    for (int f1 = 0; f1 < 16; ++f1) {
      int f  = (f1 << 8) + tid;
      int fp = (4096 - f) & 4095;
      float2 A  = Z[f ^ x1];
      float2 Bv = Z[fp ^ ((fp >> 4) & 15)];
      float ur = A.x + Bv.x, ui = A.y - Bv.y;
      float vr = A.x - Bv.x, vi = -A.y - Bv.y;
      float xr = ur*vr - ui*vi, xi = ur*vi + ui*vr;
      x[f1] = make_float2(-xi * scale, xr * scale);
    }
  }

  // prefetch V row into registers (latency hidden under inverse FFT)
  float4 v4s[4];
#pragma unroll
  for (int mm = 0; mm < 4; ++mm)
    v4s[mm] = *(const float4*)&Vt[row + (tid << 2) + (mm << 10)];

  // ======== inverse FFT ========
  fft16<1>(x);
  twiddle_chain(x, PI2 * (float)tid / 4096.f);
  __syncthreads();
#pragma unroll
  for (int k = 0; k < 16; ++k) Z[(k << 8) + tid] = x[k];
  __syncthreads();
  {
    const int k1 = tid >> 4, b = tid & 15;
#pragma unroll
    for (int a = 0; a < 16; ++a) x[a] = Z[(k1 << 8) + (a << 4) + b];
    fft16<1>(x);
    twiddle_chain(x, PI2 * (float)b / 256.f);
    __syncthreads();
#pragma unroll
    for (int cc = 0; cc < 16; ++cc) Z[(k1 << 8) + (cc << 4) + (b ^ cc)] = x[cc];
  }
  __syncthreads();
  float rr[16];
  {
    const int k1 = tid >> 4, c = tid & 15;
#pragma unroll
    for (int bb = 0; bb < 16; ++bb) x[bb] = Z[(k1 << 8) + (c << 4) + (bb ^ c)];
    fft16<1>(x);
#pragma unroll
    for (int d = 0; d < 16; ++d) rr[d] = x[d].x;   // Rxx[k1 + 16c + 256d]
  }
  __syncthreads();                                 // Z free

  // ======== stage V0 copy + local top-5 candidates ========
  float* Vf = (float*)Z;                           // floats [0..8191]
#pragma unroll
  for (int mm = 0; mm < 4; ++mm) {
    int n0 = (tid << 2) + (mm << 10);
    *(float4*)&Vf[n0] = v4s[mm];                   // V0: floats [0..4095]
  }

  const int tbase = (tid >> 4) + ((tid & 15) << 4);
  {
    float c0v=-3e38f,c1v=-3e38f,c2v=-3e38f,c3v=-3e38f,c4v=-3e38f;
    int   c0i=0x7fffffff,c1i=0x7fffffff,c2i=0x7fffffff,c3i=0x7fffffff,c4i=0x7fffffff;
#pragma unroll
    for (int d = 0; d < 16; ++d) {
      float v = rr[d];
      int  gi = tbase + (d << 8);
      bool g0 = v > c0v, g1 = v > c1v, g2 = v > c2v, g3 = v > c3v, g4 = v > c4v;
      c4v = g3 ? c3v : (g4 ? v : c4v);  c4i = g3 ? c3i : (g4 ? gi : c4i);
      c3v = g2 ? c2v : (g3 ? v : c3v);  c3i = g2 ? c2i : (g3 ? gi : c3i);
      c2v = g1 ? c1v : (g2 ? v : c2v);  c2i = g1 ? c1i : (g2 ? gi : c2i);
      c1v = g0 ? c0v : (g1 ? v : c1v);  c1i = g0 ? c0i : (g1 ? gi : c1i);
      c0v = g0 ? v : c0v;               c0i = g0 ? gi : c0i;
    }
    // candidates at float2[2048 + tid*5 .. +4] (inside future-V1 region)
    const int cb = 2048 + tid * 5;
    Z[cb+0] = make_float2(c0v, __int_as_float(c0i));
    Z[cb+1] = make_float2(c1v, __int_as_float(c1i));
    Z[cb+2] = make_float2(c2v, __int_as_float(c2i));
    Z[cb+3] = make_float2(c3v, __int_as_float(c3i));
    Z[cb+4] = make_float2(c4v, __int_as_float(c4i));
  }
  __syncthreads();   // B1: candidates + V0 visible

  // ======== wave-0 only: top-24 via 4-run sorted merge ========
  // lane l merges runs of threads {l, l+64, l+128, l+192}  (bank-friendly)
  if (tid < 64) {
    const int cb0 = 2048 + (tid      ) * 5;
    const int cb1 = 2048 + (tid +  64) * 5;
    const int cb2 = 2048 + (tid + 128) * 5;
    const int cb3 = 2048 + (tid + 192) * 5;
    int p0 = 0, p1 = 0, p2 = 0, p3 = 0;
    float m0s = 0.f, esum = 0.f;
#pragma unroll 1
    for (int t = 0; t < TOPK; ++t) {
      float2 h0 = Z[cb0 + (p0 < 5 ? p0 : 4)];
      float2 h1 = Z[cb1 + (p1 < 5 ? p1 : 4)];
      float2 h2 = Z[cb2 + (p2 < 5 ? p2 : 4)];
      float2 h3 = Z[cb3 + (p3 < 5 ? p3 : 4)];
      float hv0 = (p0 < 5) ? h0.x : -3e38f;  int hi0 = __float_as_int(h0.y);
      float hv1 = (p1 < 5) ? h1.x : -3e38f;  int hi1 = __float_as_int(h1.y);
      float hv2 = (p2 < 5) ? h2.x : -3e38f;  int hi2 = __float_as_int(h2.y);
      float hv3 = (p3 < 5) ? h3.x : -3e38f;  int hi3 = __float_as_int(h3.y);
      float bv = hv0; int bi = hi0;
      if (hv1 > bv || (hv1 == bv && hi1 < bi)) { bv = hv1; bi = hi1; }
      if (hv2 > bv || (hv2 == bv && hi2 < bi)) { bv = hv2; bi = hi2; }
      if (hv3 > bv || (hv3 == bv && hi3 < bi)) { bv = hv3; bi = hi3; }
#pragma unroll
      for (int off = 32; off; off >>= 1) {
        float ov = __shfl_xor(bv, off);
        int   oi = __shfl_xor(bi, off);
        if (ov > bv || (ov == bv && oi < bi)) { bv = ov; bi = oi; }
      }
      p0 += (hi0 == bi) ? 1 : 0;
      p1 += (hi1 == bi) ? 1 : 0;
      p2 += (hi2 == bi) ? 1 : 0;
      p3 += (hi3 == bi) ? 1 : 0;
      if (t == 0) m0s = bv;
      float e = __expf(bv - m0s);
      esum += e;
      if (tid == 0) Z[3400 + t] = make_float2(e, __int_as_float(bi));  // pack
    }
    if (tid == 0) Z[3400 + TOPK] = make_float2(esum, 0.f);
  }
  __syncthreads();   // B2: pack written, selection done

  // ======== broadcast pack into registers (before V1 overwrites it) ========
  float wk[TOPK]; int ikr[TOPK];
#pragma unroll
  for (int t = 0; t < TOPK; ++t) {
    float2 p = Z[3400 + t];
    wk[t] = p.x;  ikr[t] = __float_as_int(p.y);
  }
  const float inv = 1.0f / Z[3400 + TOPK].x;
  __syncthreads();   // B2': pack reads complete

  // ======== stage V1 shifted copy (overwrites candidate/pack area) ========
#pragma unroll
  for (int mm = 0; mm < 4; ++mm) {
    int n0 = (tid << 2) + (mm << 10);
    float4 v = v4s[mm];
    Vf[4096 + ((n0 - 1) & 4095)] = v.x;
    Vf[4096 + n0]     = v.y;
    Vf[4096 + n0 + 1] = v.z;
    Vf[4096 + n0 + 2] = v.w;
  }
  __syncthreads();   // B3

  // ======== gather: A[l] = inv * sum_t e_t * V[(l + i_t) % N] ========
#pragma unroll
  for (int mm = 0; mm < 8; ++mm) {
    int l = (tid << 1) + (mm << 9);
    float accx = 0.f, accy = 0.f;
#pragma unroll
    for (int t = 0; t < TOPK; ++t) {
      int ik = ikr[t];
      int e  = (l + (ik & ~1)) & 4095;
      float2 vv = *(float2*)&Vf[((ik & 1) << 12) + e];
      accx += wk[t] * vv.x;
      accy += wk[t] * vv.y;
    }
    *(float2*)&At[row + l] = make_float2(accx * inv, accy * inv);
  }
}

extern "C" void kernel_launch(void* const* d_in, const int* in_sizes, int n_in,
                              void* d_out, int out_size, void* d_ws, size_t ws_size,
                              hipStream_t stream) {
  const float* Q = (const float*)d_in[0];
  const float* K = (const float*)d_in[1];
  const float* V = (const float*)d_in[2];
  float* out = (float*)d_out;
  float* wsf = (float*)d_ws;

  const int B = 16;
  const size_t SLAB = (size_t)4194304;       // B*L*D floats
  float2* ZQK = (float2*)wsf;                // 2*SLAB floats (33.5 MB)
  float*  Vt  = wsf + 2 * SLAB;
  float*  At  = Vt;   // alias: block i reads Vt row i (to regs) before writing At row i

  dim3 blk(256);
  transposeQK<<<dim3(64, B), blk, 0, stream>>>(Q, K, ZQK);
  transpose64<<<dim3(64, B), blk, 0, stream>>>(V, Vt, 4096, 64);

  corr_kernel<<<dim3(B * 64), blk, 0, stream>>>(ZQK, Vt, At);

  transpose64<<<dim3(64, B), blk, 0, stream>>>(At, out, 64, 4096);
}